// Round 1
// baseline (98.078 us; speedup 1.0000x reference)
//
#include <hip/hip_runtime.h>

// Subtraction2: out[n, c*49 + kh*7 + kw, h, w] = x1[n,c,h,w] - x2[n,c,refl(h+kh-3),refl(w+kw-3)]
// N=8 C=64 H=W=56 K=7 PAD=3 STRIDE=1 DIL=1 -> h_out=w_out=56, x1c == x1.
// Write-BW-bound: 314.7 MB out, ~13 MB in (L2/L3 resident).

constexpr int N_  = 8;
constexpr int C_  = 64;
constexpr int H_  = 56;
constexpr int W_  = 56;
constexpr int K_  = 7;
constexpr int PAD_ = 3;
constexpr int W4_ = W_ / 4;                                   // 14 float4 per row
constexpr int TOTAL4_ = N_ * C_ * K_ * K_ * H_ * W4_;         // 19,668,992

__device__ __forceinline__ int refl(int i) {
    // reflect (no edge duplication): valid for i in [-PAD_, H_-1+PAD_]
    i = (i < 0) ? -i : i;
    return (i < H_) ? i : (2 * (H_ - 1) - i);
}

__global__ __launch_bounds__(256)
void sub2_kernel(const float* __restrict__ x1,
                 const float* __restrict__ x2,
                 float* __restrict__ out)
{
    int idx = blockIdx.x * blockDim.x + threadIdx.x;
    if (idx >= TOTAL4_) return;

    // idx = ((((n*C_ + c)*49 + k)*H_ + h)*W4_ + w4)  -- matches output flat order
    int w4 = idx % W4_;
    int t  = idx / W4_;
    int h  = t % H_;        t /= H_;
    int k  = t % (K_ * K_); t /= (K_ * K_);
    int c  = t % C_;
    int n  = t / C_;
    int kh = k / K_;
    int kw = k % K_;

    int hs = refl(h + kh - PAD_);

    const float* __restrict__ x1row = x1 + (((n * C_ + c) * H_ + h) * W_);
    const float* __restrict__ x2row = x2 + (((n * C_ + c) * H_ + hs) * W_);

    int w0 = w4 * 4;
    float4 a = *reinterpret_cast<const float4*>(x1row + w0);

    float b0, b1, b2, b3;
    {
        int base = w0 + kw - PAD_;
        b0 = x2row[refl(base + 0)];
        b1 = x2row[refl(base + 1)];
        b2 = x2row[refl(base + 2)];
        b3 = x2row[refl(base + 3)];
    }

    float4 r;
    r.x = a.x - b0;
    r.y = a.y - b1;
    r.z = a.z - b2;
    r.w = a.w - b3;

    *reinterpret_cast<float4*>(out + (size_t)idx * 4) = r;
}

extern "C" void kernel_launch(void* const* d_in, const int* in_sizes, int n_in,
                              void* d_out, int out_size, void* d_ws, size_t ws_size,
                              hipStream_t stream) {
    const float* x1 = (const float*)d_in[0];
    const float* x2 = (const float*)d_in[1];
    float* out = (float*)d_out;

    int blocks = (TOTAL4_ + 255) / 256;
    sub2_kernel<<<blocks, 256, 0, stream>>>(x1, x2, out);
}

// Round 2
// 63.870 us; speedup vs baseline: 1.5356x; 1.5356x over previous
//
#include <hip/hip_runtime.h>

// Subtraction2: out[n, c*49 + kh*7 + kw, h, w] = x1[n,c,h,w] - x2[n,c,refl(h+kh-3),refl(w+kw-3)]
// N=8 C=64 H=W=56 K=7 PAD=3 -> h_out=w_out=56, x1c == x1.
// Write-BW-bound: 314.7 MB out. fillBuffer on this box: 6.9 TB/s -> ~46us floor.
// R1: thread = (n,c,kh,h,w4), loops kw 0..6. 18 VMEM / 28 outputs (was 42).

constexpr int N_   = 8;
constexpr int C_   = 64;
constexpr int H_   = 56;
constexpr int W_   = 56;
constexpr int K_   = 7;
constexpr int PAD_ = 3;
constexpr int W4_  = W_ / 4;                 // 14
constexpr int TPC_ = K_ * H_ * W4_;          // threads per (n,c): 7*56*14 = 5488
constexpr int HW_  = H_ * W_;                // 3136 floats per plane

__device__ __forceinline__ int refl(int i) {
    // jnp reflect pad (no edge duplication): valid for i in [-PAD_, H_-1+PAD_]
    i = (i < 0) ? -i : i;
    return (i < H_) ? i : (2 * (H_ - 1) - i);
}

__global__ __launch_bounds__(256)
void sub2_kernel(const float* __restrict__ x1,
                 const float* __restrict__ x2,
                 float* __restrict__ out)
{
    int t = blockIdx.x * 256 + threadIdx.x;
    if (t >= TPC_) return;

    // t = (kh*H_ + h)*W4_ + w4  (w4 fastest -> waves store contiguous 1KB lines)
    int w4 = t % W4_;
    int r  = t / W4_;
    int h  = r % H_;
    int kh = r / H_;

    int nc = blockIdx.y;                      // n*C_ + c
    int hs = refl(h + kh - PAD_);

    const float* __restrict__ x1row = x1 + ((size_t)nc * H_ + h) * W_;
    const float* __restrict__ x2row = x2 + ((size_t)nc * H_ + hs) * W_;

    int w0 = w4 * 4;
    float4 a = *reinterpret_cast<const float4*>(x1row + w0);

    // x2 window covering all 7 kw shifts: indices w0-3 .. w0+6
    float b[10];
#pragma unroll
    for (int j = 0; j < 10; ++j)
        b[j] = x2row[refl(w0 - PAD_ + j)];

    float* __restrict__ obase =
        out + (((size_t)nc * (K_ * K_) + kh * K_) * H_ + h) * W_ + w0;

#pragma unroll
    for (int kw = 0; kw < K_; ++kw) {
        float4 v;
        v.x = a.x - b[kw + 0];
        v.y = a.y - b[kw + 1];
        v.z = a.z - b[kw + 2];
        v.w = a.w - b[kw + 3];
        *reinterpret_cast<float4*>(obase + (size_t)kw * HW_) = v;
    }
}

extern "C" void kernel_launch(void* const* d_in, const int* in_sizes, int n_in,
                              void* d_out, int out_size, void* d_ws, size_t ws_size,
                              hipStream_t stream) {
    const float* x1 = (const float*)d_in[0];
    const float* x2 = (const float*)d_in[1];
    float* out = (float*)d_out;

    dim3 grid((TPC_ + 255) / 256, N_ * C_);   // 22 x 512 blocks
    sub2_kernel<<<grid, 256, 0, stream>>>(x1, x2, out);
}

// Round 4
// 62.126 us; speedup vs baseline: 1.5787x; 1.0281x over previous
//
#include <hip/hip_runtime.h>

// Subtraction2: out[n, c*49 + kh*7 + kw, h, w] = x1[n,c,h,w] - x2[n,c,refl(h+kh-3),refl(w+kw-3)]
// N=8 C=64 H=W=56 K=7 PAD=3 -> h_out=w_out=56, x1c == x1.
// Write-BW-bound: 314.7 MB out; fill rate on this box 6.9 TB/s -> ~47us floor. R1 = 63.9us.
// R2/R3: x2 window via 3 aligned float4 loads + constant-index selects (VMEM 18->11/wave),
//        nontemporal stores via native ext_vector type (HIP_vector_type rejected by builtin).

typedef float f4 __attribute__((ext_vector_type(4)));

constexpr int N_   = 8;
constexpr int C_   = 64;
constexpr int H_   = 56;
constexpr int W_   = 56;
constexpr int K_   = 7;
constexpr int PAD_ = 3;
constexpr int W4_  = W_ / 4;                 // 14
constexpr int TPC_ = K_ * H_ * W4_;          // threads per (n,c): 7*56*14 = 5488
constexpr int HW_  = H_ * W_;                // 3136 floats per plane

__device__ __forceinline__ int refl(int i) {
    i = (i < 0) ? -i : i;
    return (i < H_) ? i : (2 * (H_ - 1) - i);
}

__global__ __launch_bounds__(256)
void sub2_kernel(const float* __restrict__ x1,
                 const float* __restrict__ x2,
                 float* __restrict__ out)
{
    int t = blockIdx.x * 256 + threadIdx.x;
    if (t >= TPC_) return;

    // t = (kh*H_ + h)*W4_ + w4  (w4 fastest -> waves store contiguous 1KB lines)
    int w4 = t % W4_;
    int r  = t / W4_;
    int h  = r % H_;
    int kh = r / H_;

    int nc = blockIdx.y;                      // n*C_ + c
    int hs = refl(h + kh - PAD_);

    const float* __restrict__ x1row = x1 + ((size_t)nc * H_ + h) * W_;
    const float* __restrict__ x2row = x2 + ((size_t)nc * H_ + hs) * W_;

    int w0 = w4 * 4;
    f4 a = *reinterpret_cast<const f4*>(x1row + w0);

    // Load 12 contiguous floats covering every source index this thread can need.
    // wb = clamp(w0-4, 0, 44): interior threads -> f[j+1] == x2row[w0-3+j];
    // w4==0  -> f == x2row[0..11],  needed refl'd indices 3,2,1,0,1..6
    // w4==13 -> f == x2row[44..55], needed 49..55,54,53,52 => f[5..11],f[10],f[9],f[8]
    int wb = w0 - 4;
    wb = wb < 0 ? 0 : (wb > 44 ? 44 : wb);
    f4 f0 = *reinterpret_cast<const f4*>(x2row + wb);
    f4 f1 = *reinterpret_cast<const f4*>(x2row + wb + 4);
    f4 f2 = *reinterpret_cast<const f4*>(x2row + wb + 8);
    float f[12] = {f0.x, f0.y, f0.z, f0.w, f1.x, f1.y, f1.z, f1.w,
                   f2.x, f2.y, f2.z, f2.w};

    bool eL = (w4 == 0);
    bool eR = (w4 == W4_ - 1);

    // b[j] = x2row[refl(w0-3+j)], j = 0..9, via compile-time-constant indices only.
    constexpr int pL[10] = {3, 2, 1, 0, 1, 2, 3, 4, 5, 6};
    constexpr int pR[10] = {5, 6, 7, 8, 9, 10, 11, 10, 9, 8};
    float b[10];
#pragma unroll
    for (int j = 0; j < 10; ++j)
        b[j] = eL ? f[pL[j]] : (eR ? f[pR[j]] : f[j + 1]);

    float* __restrict__ obase =
        out + (((size_t)nc * (K_ * K_) + kh * K_) * H_ + h) * W_ + w0;

#pragma unroll
    for (int kw = 0; kw < K_; ++kw) {
        f4 v;
        v.x = a.x - b[kw + 0];
        v.y = a.y - b[kw + 1];
        v.z = a.z - b[kw + 2];
        v.w = a.w - b[kw + 3];
        __builtin_nontemporal_store(v, reinterpret_cast<f4*>(obase + (size_t)kw * HW_));
    }
}

extern "C" void kernel_launch(void* const* d_in, const int* in_sizes, int n_in,
                              void* d_out, int out_size, void* d_ws, size_t ws_size,
                              hipStream_t stream) {
    const float* x1 = (const float*)d_in[0];
    const float* x2 = (const float*)d_in[1];
    float* out = (float*)d_out;

    dim3 grid((TPC_ + 255) / 256, N_ * C_);   // 22 x 512 blocks
    sub2_kernel<<<grid, 256, 0, stream>>>(x1, x2, out);
}